// Round 8
// baseline (622.149 us; speedup 1.0000x reference)
//
#include <hip/hip_runtime.h>

#define HW 4096

// ------- kernel A: fused instance-norm stats + ref_score (1 HBM pass over corr)
// blocks 0..511: one (q,r,ns) group each (18 ch x 4096 px = 295 KB).
//   pass 1: per-channel sum/sumsq (reg acc + xor-shuffle + LDS combine)
//   pass 2: re-read (L2/L3-hot) -> rs = mean_c(x*scl+shf)/18
// ss output: float2 (scl, shf) interleaved.
// blocks 512..660: weight transposes (conv + MLP), independent work.
__global__ __launch_bounds__(256) void k_statsrs(
    const float* __restrict__ corr, float2* __restrict__ ss,
    float* __restrict__ rs,
    const float* __restrict__ p0, const float* __restrict__ p1,
    const float* __restrict__ p2, const float* __restrict__ p3,
    const float* __restrict__ p4, const float* __restrict__ p5,
    float* __restrict__ wT, const float* __restrict__ w1s,
    const float* __restrict__ w2s, const float* __restrict__ w1c,
    const float* __restrict__ w2c, float* __restrict__ wm) {
  int t = threadIdx.x;
  if (blockIdx.x >= 512) {
    int b = blockIdx.x - 512;  // 96 conv chunks + 53 mlp chunks
    if (b < 96) {
      int arr = b >> 4;
      int chunk = b & 15;
      const float* src = (arr == 0) ? p0
                         : (arr == 1) ? p1
                         : (arr == 2) ? p2
                         : (arr == 3) ? p3
                         : (arr == 4) ? p4 : p5;
      float* dst = wT + arr * 36864;
#pragma unroll
      for (int i = 0; i < 9; i++) {
        int e = chunk * 2304 + i * 256 + t;  // 0..36863
        int oc = e / 576;
        int rem = e - oc * 576;  // ic*9+j
        dst[rem * 64 + oc] = src[e];
      }
    } else {
      int i = (b - 96) * 256 + t;
      if (i < 4608) {
        int c = i >> 6, o = i & 63;
        wm[i] = w1s[o * 72 + c];
      } else if (i < 8704) {
        int j = i - 4608;
        int c = j >> 6, o = j & 63;
        wm[i] = w2s[o * 64 + c];
      } else if (i < 9472) {
        int j = i - 8704;
        int c = j >> 6, o = j & 63;
        wm[i] = w1c[o * 12 + c];
      } else if (i < 13568) {
        int j = i - 9472;
        int c = j >> 6, o = j & 63;
        wm[i] = w2c[o * 64 + c];
      }
    }
    return;
  }
  int g = blockIdx.x;  // (q*32+r)*4+ns
  const float4* p = (const float4*)(corr + (size_t)g * 18 * HW);

  // ---- pass 1: per-channel stats, 18 reg accumulators (static idx only)
  float s[18], s2[18];
#pragma unroll
  for (int c = 0; c < 18; c++) { s[c] = 0.f; s2[c] = 0.f; }
#pragma unroll
  for (int c = 0; c < 18; c++) {
#pragma unroll
    for (int i = 0; i < 4; i++) {
      float4 v = p[(c << 10) + (i << 8) + t];
      s[c] += v.x + v.y + v.z + v.w;
      s2[c] += v.x * v.x + v.y * v.y + v.z * v.z + v.w * v.w;
    }
  }
#pragma unroll
  for (int c = 0; c < 18; c++) {
#pragma unroll
    for (int o = 1; o < 64; o <<= 1) {
      s[c] += __shfl_xor(s[c], o, 64);
      s2[c] += __shfl_xor(s2[c], o, 64);
    }
  }
  __shared__ float lds_s[4][18], lds_s2[4][18];
  __shared__ float lds_scl[18], lds_shf[18];
  int wid = t >> 6;
  int ln = t & 63;
  if (ln < 18) {
    float vs = 0.f, vs2 = 0.f;
#pragma unroll
    for (int c = 0; c < 18; c++) {
      vs = (ln == c) ? s[c] : vs;
      vs2 = (ln == c) ? s2[c] : vs2;
    }
    lds_s[wid][ln] = vs;
    lds_s2[wid][ln] = vs2;
  }
  __syncthreads();
  if (t < 18) {
    float S = lds_s[0][t] + lds_s[1][t] + lds_s[2][t] + lds_s[3][t];
    float S2 = lds_s2[0][t] + lds_s2[1][t] + lds_s2[2][t] + lds_s2[3][t];
    float m = S * (1.f / HW);
    float var = S2 * (1.f / HW) - m * m;
    float r = rsqrtf(var + 1e-5f);
    ss[g * 18 + t] = make_float2(r, -m * r);
    lds_scl[t] = r;
    lds_shf[t] = -m * r;
  }
  __syncthreads();

  // ---- pass 2: re-read (cache-hot), rs = (sum_c x*scl + sum_c shf)/18
  float shsum = 0.f;
#pragma unroll
  for (int c = 0; c < 18; c++) shsum += lds_shf[c];
  const float inv = 1.f / 18.f;
#pragma unroll
  for (int i = 0; i < 4; i++) {
    float4 acc = make_float4(0.f, 0.f, 0.f, 0.f);
#pragma unroll
    for (int c = 0; c < 18; c++) {
      float4 v = p[(c << 10) + (i << 8) + t];
      float sc = lds_scl[c];
      acc.x = fmaf(v.x, sc, acc.x);
      acc.y = fmaf(v.y, sc, acc.y);
      acc.z = fmaf(v.z, sc, acc.z);
      acc.w = fmaf(v.w, sc, acc.w);
    }
    float4 o;
    o.x = (acc.x + shsum) * inv;
    o.y = (acc.y + shsum) * inv;
    o.z = (acc.z + shsum) * inv;
    o.w = (acc.w + shsum) * inv;
    ((float4*)(rs + (size_t)g * HW))[(i << 8) + t] = o;
  }
}

// ---------------- kernel C: top-4 of 32, LDS-staged ----------------
__global__ __launch_bounds__(256) void k_topk(const float* __restrict__ rs,
                                              int* __restrict__ topidx) {
  __shared__ float st[32 * 256];  // 32 KB
  int b = blockIdx.x;             // 256 = q*4ns*16pxc
  int pxc = b & 15;
  int ns = (b >> 4) & 3;
  int q = b >> 6;
  int t = threadIdx.x;
  int pxb = pxc * 256;
#pragma unroll 8
  for (int r = 0; r < 32; r++)
    st[r * 256 + t] = rs[((q * 32 + r) * 4 + ns) * HW + pxb + t];
  __syncthreads();
  float v[32];
#pragma unroll
  for (int r = 0; r < 32; r++) v[r] = st[r * 256 + t];
  unsigned mask = 0;
  int sel[4];
#pragma unroll
  for (int k = 0; k < 4; k++) {
    float best = -3.4e38f;
    int bi = 0;
#pragma unroll
    for (int r = 0; r < 32; r++) {
      bool take = (!(mask & (1u << r))) && (v[r] > best);
      best = take ? v[r] : best;
      bi = take ? r : bi;
    }
    sel[k] = bi;
    mask |= (1u << bi);
  }
  ((int4*)topidx)[(q * 4 + ns) * HW + pxb + t] =
      make_int4(sel[0], sel[1], sel[2], sel[3]);
}

// ---- kernel D: stream-select gather + both MLPs, 512 thr, 8 osegs x 8 ch.
// grid 1024 = q(4) x pxg(256 groups of 16 px).
// thread = oseg(8) x ns(4) x pxi(16).  k = oseg>>1, ch-half = oseg&1.
// Gather: stream ALL 32 candidate rows coalesced (16-px contiguous lines),
// keep the row matching per-pixel rk via cndmask into static v[9].
// Unique corr traffic = 1 full pass (151 MB, coalesced); 4x k-redundancy
// is same-address across waves -> L2 broadcast.
// LDS: lx 18KB + lh 16KB + lxsc 3KB = 37.4KB.
__global__ __launch_bounds__(512, 4) void k_mlp3(
    const float* __restrict__ corr, const float2* __restrict__ ss,
    const int* __restrict__ topidx, const float* __restrict__ wm,
    const float* __restrict__ b1s, const float* __restrict__ b2s,
    const float* __restrict__ b1c, const float* __restrict__ b2c,
    float* __restrict__ xs, float* __restrict__ xc) {
  __shared__ float lx[72 * 64];    // gathered+normed x; later reused for a
  __shared__ float lh[64 * 64];    // hidden exchange
  __shared__ float lxsc[12 * 64];  // level means (score-path input)
  int blk = blockIdx.x;
  int q = blk >> 8, pxg = blk & 255;
  int t = threadIdx.x;
  int wi = t & 63;      // ns*16 + pxi
  int oseg = t >> 6;    // wave-uniform 0..7
  int ns = (t >> 4) & 3;
  int pxi = t & 15;
  int px = pxg * 16 + pxi;
  int k = oseg >> 1;        // wave-uniform knn slot
  int ch0 = (oseg & 1) * 9; // wave-uniform channel half

  int4 ti = ((const int4*)topidx)[(q * 4 + ns) * HW + px];
  int rk = (k == 0) ? ti.x : (k == 1) ? ti.y : (k == 2) ? ti.z : ti.w;

  // ---- coalesced stream-select over all 32 rows
  const float* cb = corr + ((size_t)((q * 32) * 4 + ns) * 18 + ch0) * HW + px;
  float v[9];
#pragma unroll
  for (int j = 0; j < 9; j++) v[j] = 0.f;
#pragma unroll 4
  for (int r = 0; r < 32; r++) {
    const float* pr = cb + (size_t)r * (72 * HW);
    float x[9];
#pragma unroll
    for (int j = 0; j < 9; j++) x[j] = pr[(size_t)j * HW];
    bool m = (r == rk);
#pragma unroll
    for (int j = 0; j < 9; j++) v[j] = m ? x[j] : v[j];
  }
  // normalize with selected row's stats (tiny scattered loads, L2-hot)
  const float2* sb = ss + ((q * 32 + rk) * 4 + ns) * 18 + ch0;
  float2 sh[9];
#pragma unroll
  for (int j = 0; j < 9; j++) sh[j] = sb[j];
#pragma unroll
  for (int j = 0; j < 9; j++)
    lx[(k * 18 + ch0 + j) * 64 + wi] = fmaf(v[j], sh[j].x, sh[j].y);
  __syncthreads();  // #1: lx complete

  // level means: lxsc[l][col], 768 entries over 512 threads
#pragma unroll
  for (int m = 0; m < 2; m++) {
    int idx = m * 512 + t;
    if (idx < 768) {
      int l = idx >> 6, w2 = idx & 63;
      float sm = 0.f;
#pragma unroll
      for (int j = 0; j < 6; j++) sm += lx[(l * 6 + j) * 64 + w2];
      lxsc[l * 64 + w2] = sm * (1.f / 6.f);
    }
  }

  // ---- scale path layer 1: 72 -> 8 (this thread's segment)
  float h[8];
  const float* bp1 = b1s + oseg * 8;
#pragma unroll
  for (int o = 0; o < 8; o++) h[o] = bp1[o];
#pragma unroll
  for (int c = 0; c < 72; c++) {
    float x = lx[c * 64 + wi];
    const float* wr = wm + c * 64 + oseg * 8;  // wave-uniform -> s_load
#pragma unroll
    for (int o = 0; o < 8; o++) h[o] = fmaf(wr[o], x, h[o]);
  }
#pragma unroll
  for (int o = 0; o < 8; o++) lh[(oseg * 8 + o) * 64 + wi] = fmaxf(h[o], 0.f);
  __syncthreads();  // #2: lh + lxsc complete, all lx reads (l1) done

  // ---- scale path layer 2: 64 -> 8
  float a[8];
  const float* bp2 = b2s + oseg * 8;
#pragma unroll
  for (int o = 0; o < 8; o++) a[o] = bp2[o];
#pragma unroll
  for (int c = 0; c < 64; c++) {
    float x = lh[c * 64 + wi];
    const float* wr = wm + 4608 + c * 64 + oseg * 8;
#pragma unroll
    for (int o = 0; o < 8; o++) a[o] = fmaf(wr[o], x, a[o]);
  }
#pragma unroll
  for (int o = 0; o < 8; o++) lx[(oseg * 8 + o) * 64 + wi] = a[o];
  __syncthreads();  // #3: a staged in lx, all lh reads (l2) done

  // ns-max + store xs (2 per thread); score-path l1 in same phase
#pragma unroll
  for (int m = 0; m < 2; m++) {
    int idx = m * 512 + t;
    int oc = idx >> 4, ppx = idx & 15;
    float v2 = lx[oc * 64 + ppx];
    v2 = fmaxf(v2, lx[oc * 64 + 16 + ppx]);
    v2 = fmaxf(v2, lx[oc * 64 + 32 + ppx]);
    v2 = fmaxf(v2, lx[oc * 64 + 48 + ppx]);
    xs[(size_t)(q * 64 + oc) * HW + pxg * 16 + ppx] = v2;
  }
  const float* bc1 = b1c + oseg * 8;
#pragma unroll
  for (int o = 0; o < 8; o++) h[o] = bc1[o];
#pragma unroll
  for (int c = 0; c < 12; c++) {
    float x = lxsc[c * 64 + wi];
    const float* wr = wm + 8704 + c * 64 + oseg * 8;
#pragma unroll
    for (int o = 0; o < 8; o++) h[o] = fmaf(wr[o], x, h[o]);
  }
#pragma unroll
  for (int o = 0; o < 8; o++) lh[(oseg * 8 + o) * 64 + wi] = fmaxf(h[o], 0.f);
  __syncthreads();  // #4: score-h in lh, all xs-max lx reads done

  // ---- score path layer 2: 64 -> 8
  const float* bc2 = b2c + oseg * 8;
#pragma unroll
  for (int o = 0; o < 8; o++) a[o] = bc2[o];
#pragma unroll
  for (int c = 0; c < 64; c++) {
    float x = lh[c * 64 + wi];
    const float* wr = wm + 9472 + c * 64 + oseg * 8;
#pragma unroll
    for (int o = 0; o < 8; o++) a[o] = fmaf(wr[o], x, a[o]);
  }
#pragma unroll
  for (int o = 0; o < 8; o++) lx[(oseg * 8 + o) * 64 + wi] = a[o];
  __syncthreads();  // #5

  // ns-max + store xc
#pragma unroll
  for (int m = 0; m < 2; m++) {
    int idx = m * 512 + t;
    int oc = idx >> 4, ppx = idx & 15;
    float v2 = lx[oc * 64 + ppx];
    v2 = fmaxf(v2, lx[oc * 64 + 16 + ppx]);
    v2 = fmaxf(v2, lx[oc * 64 + 32 + ppx]);
    v2 = fmaxf(v2, lx[oc * 64 + 48 + ppx]);
    xc[(size_t)(q * 64 + oc) * HW + pxg * 16 + ppx] = v2;
  }
}

// ---- merged big 3x3 conv v3: 2 rows x 16 oc per thread (og=4).
// grid 384 = hi(12: og*3+head)*32 + q*8 + rt.  Tile: 8 out rows x 64 cols.
// LDS 16ic x 10 rows x 72 stride (data at col 4..67, pads col 3 & 68) = 46 KB.
template <bool RELU>
__global__ __launch_bounds__(256) void k_conv3h(
    const float* __restrict__ in0, const float* __restrict__ in1,
    const float* __restrict__ in2, const float* __restrict__ w0,
    const float* __restrict__ w1, const float* __restrict__ w2,
    const float* __restrict__ bb0, const float* __restrict__ bb1,
    const float* __restrict__ bb2, float* __restrict__ o0,
    float* __restrict__ o1, float* __restrict__ o2) {
  __shared__ float tile[16 * 10 * 72];  // 46.1 KB -> 3 blocks/CU
  int b = blockIdx.x;
  int hi = b >> 5;  // og*3 + head, og in 0..3
  int og = hi / 3;
  int head = hi - og * 3;
  int q = (b >> 3) & 3;
  int rt = b & 7;
  const float* in = head == 0 ? in0 : head == 1 ? in1 : in2;
  const float* wT = head == 0 ? w0 : head == 1 ? w1 : w2;
  const float* bb = head == 0 ? bb0 : head == 1 ? bb1 : bb2;
  float* outp = head == 0 ? o0 : head == 1 ? o1 : o2;

  int t = threadIdx.x;
  int w = t & 63;
  int wr = t >> 6;       // 0..3 (wave-uniform): thread rows 2wr, 2wr+1
  int lane4 = t & 15;    // staging: float4 col
  int rgrp = t >> 4;     // staging: 16 rows/pass
  float acc[2][16];
#pragma unroll
  for (int pr = 0; pr < 2; pr++)
#pragma unroll
    for (int o = 0; o < 16; o++) acc[pr][o] = 0.f;
  const float* inq = in + (size_t)q * 64 * HW;

  for (int icc = 0; icc < 4; icc++) {
    __syncthreads();
    // edge pads (rows 0..159): col 3 (img -1) and col 68 (img 64)
    if (t < 160) { tile[t * 72 + 3] = 0.f; tile[t * 72 + 68] = 0.f; }
    // stage 16 ic x 10 rows x 64 cols as float4
#pragma unroll
    for (int p = 0; p < 10; p++) {
      int idx = p * 16 + rgrp;  // 0..159
      int ch = idx / 10;
      int r = idx - ch * 10;
      int grow = rt * 8 + r - 1;
      float4 val = make_float4(0.f, 0.f, 0.f, 0.f);
      if (grow >= 0 && grow < 64)
        val = *(const float4*)(inq + (size_t)(icc * 16 + ch) * HW + grow * 64 +
                               lane4 * 4);
      *(float4*)(tile + idx * 72 + 4 + lane4 * 4) = val;
    }
    __syncthreads();
#pragma unroll 2
    for (int ic = 0; ic < 16; ic++) {
      // x window: 4 tile rows x 3 cols
      float xv[4][3];
      const float* tb = tile + (ic * 10 + wr * 2) * 72 + w + 3;
#pragma unroll
      for (int rr = 0; rr < 4; rr++)
#pragma unroll
        for (int dc = 0; dc < 3; dc++) xv[rr][dc] = tb[rr * 72 + dc];
      const float* wb = wT + (size_t)(icc * 16 + ic) * 9 * 64 + og * 16;
#pragma unroll
      for (int dr = 0; dr < 3; dr++)
#pragma unroll
        for (int dc = 0; dc < 3; dc++) {
          const float* wv = wb + (dr * 3 + dc) * 64;
#pragma unroll
          for (int o = 0; o < 16; o++) {
            float wj = wv[o];
            acc[0][o] = fmaf(wj, xv[0 + dr][dc], acc[0][o]);
            acc[1][o] = fmaf(wj, xv[1 + dr][dc], acc[1][o]);
          }
        }
    }
  }
#pragma unroll
  for (int pr = 0; pr < 2; pr++) {
    int orow = rt * 8 + wr * 2 + pr;
#pragma unroll
    for (int o = 0; o < 16; o++) {
      float rz = acc[pr][o] + bb[og * 16 + o];
      if (RELU) rz = fmaxf(rz, 0.f);
      outp[((size_t)q * 64 + og * 16 + o) * HW + orow * 64 + w] = rz;
    }
  }
}

// ---- merged small 3x3 conv (heads: OC=1,2,1), 1-row blocks ----
__global__ __launch_bounds__(256) void k_convSh(
    const float* __restrict__ in0, const float* __restrict__ in1,
    const float* __restrict__ in2, const float* __restrict__ wt0,
    const float* __restrict__ wt1, const float* __restrict__ wt2,
    const float* __restrict__ bb0, const float* __restrict__ bb1,
    const float* __restrict__ bb2, float* __restrict__ o0,
    float* __restrict__ o1, float* __restrict__ o2) {
  __shared__ float tile[64 * 3 * 66];  // 50.7 KB
  __shared__ float red[4 * 2 * 64];
  int b = blockIdx.x;  // 768 = head*256 + q*64 + row
  int head = b >> 8;
  int q = (b >> 6) & 3;
  int row = b & 63;
  const float* in = head == 0 ? in0 : head == 1 ? in1 : in2;
  const float* wt = head == 0 ? wt0 : head == 1 ? wt1 : wt2;
  const float* bb = head == 0 ? bb0 : head == 1 ? bb1 : bb2;
  float* outp = head == 0 ? o0 : head == 1 ? o1 : o2;
  int noc = (head == 1) ? 2 : 1;

  int t = threadIdx.x;
  int w = t & 63;
  int sub = t >> 6;
  if (t < 192) { tile[t * 66] = 0.f; tile[t * 66 + 65] = 0.f; }
  __syncthreads();
  const float* inq = in + (size_t)q * 64 * HW;
#pragma unroll
  for (int i = 0; i < 48; i++) {
    int idx = i * 4 + sub;
    int ic = idx / 3;
    int r = idx - ic * 3;
    int grow = row + r - 1;
    float val = 0.f;
    if (grow >= 0 && grow < 64) val = inq[(size_t)ic * HW + grow * 64 + w];
    tile[idx * 66 + 1 + w] = val;
  }
  __syncthreads();
  float acc0 = 0.f, acc1 = 0.f;
#pragma unroll 4
  for (int i = 0; i < 16; i++) {
    int ic = sub * 16 + i;
    float x[9];
#pragma unroll
    for (int dr = 0; dr < 3; dr++)
#pragma unroll
      for (int dc = 0; dc < 3; dc++)
        x[dr * 3 + dc] = tile[(ic * 3 + dr) * 66 + w + dc];
    const float* wb = wt + (size_t)ic * 9;
#pragma unroll
    for (int j = 0; j < 9; j++) acc0 += wb[j] * x[j];
    if (noc == 2) {
      const float* wb1 = wt + 576 + (size_t)ic * 9;
#pragma unroll
      for (int j = 0; j < 9; j++) acc1 += wb1[j] * x[j];
    }
  }
  red[(sub * 2 + 0) * 64 + w] = acc0;
  if (noc == 2) red[(sub * 2 + 1) * 64 + w] = acc1;
  __syncthreads();
  if (t < 128) {
    int o = t >> 6;
    if (o < noc) {
      float s = red[(0 * 2 + o) * 64 + w] + red[(1 * 2 + o) * 64 + w] +
                red[(2 * 2 + o) * 64 + w] + red[(3 * 2 + o) * 64 + w] + bb[o];
      outp[((size_t)q * noc + o) * HW + row * 64 + w] = s;
    }
  }
}

// ---------------- final: argmax + pos/scl ----------------
__global__ __launch_bounds__(256) void k_final(const float* __restrict__ scores,
                                               const float* __restrict__ scales,
                                               const float* __restrict__ offsets,
                                               float* __restrict__ pos,
                                               float* __restrict__ sclo) {
  int q = blockIdx.x, t = threadIdx.x;
  float best = -3.4e38f;
  int bi = 1 << 30;
  for (int i = t; i < HW; i += 256) {
    float v = scores[q * HW + i];
    if (v > best) { best = v; bi = i; }
  }
  __shared__ float bv[256];
  __shared__ int bix[256];
  bv[t] = best;
  bix[t] = bi;
  __syncthreads();
  for (int s = 128; s > 0; s >>= 1) {
    if (t < s) {
      if (bv[t + s] > bv[t] || (bv[t + s] == bv[t] && bix[t + s] < bix[t])) {
        bv[t] = bv[t + s];
        bix[t] = bix[t + s];
      }
    }
    __syncthreads();
  }
  if (t == 0) {
    int sid = bix[0];
    int sy = sid >> 6, sx = sid & 63;
    float o0 = offsets[(q * 2 + 0) * HW + sid];
    float o1 = offsets[(q * 2 + 1) * HW + sid];
    pos[q * 2 + 0] = ((float)sx + o0 + 0.5f) * 8.f - 0.5f;
    pos[q * 2 + 1] = ((float)sy + o1 + 0.5f) * 8.f - 0.5f;
    sclo[q] = exp2f(scales[q * HW + sid]);
  }
}

extern "C" void kernel_launch(void* const* d_in, const int* in_sizes, int n_in,
                              void* d_out, int out_size, void* d_ws, size_t ws_size,
                              hipStream_t stream) {
  const float* corr = (const float*)d_in[0];
  const float* w1s = (const float*)d_in[1];
  const float* b1s = (const float*)d_in[2];
  const float* w2s = (const float*)d_in[3];
  const float* b2s = (const float*)d_in[4];
  const float* w1c = (const float*)d_in[5];
  const float* b1c = (const float*)d_in[6];
  const float* w2c = (const float*)d_in[7];
  const float* b2c = (const float*)d_in[8];

  float* out = (float*)d_out;
  float* pos = out;                   // (4,2)
  float* sclo = out + 8;              // (4,)
  float* scores = out + 12;           // (4,1,64,64)
  float* scales = out + 12 + 16384;   // (4,1,64,64)
  float* offsets = out + 12 + 32768;  // (4,2,64,64)

  char* ws = (char*)d_ws;
  float2* st_ss = (float2*)(ws + 0);      // 72 KB (scl,shf interleaved)
  int* topidx = (int*)(ws + 73728);       // 1 MB
  float* rs = (float*)(ws + 1122304);     // 8.39 MB (dead after k_topk)
  float* wT = (float*)(ws + 19996672);    // 884 KB (big-conv transposed w)
  float* wmT = (float*)(ws + 20881408);   // 54 KB (MLP transposed w)
  float* xs = (float*)(ws + 20971520);    // 4.19 MB
  float* xc = (float*)(ws + 25165824);    // 4.19 MB  (total 29.4 MB)
  // t1/t2 reuse dead regions (stream-ordered):
  float* t1s = rs;                           // rs dead after k_topk
  float* t1o = (float*)((char*)rs + 4194304);
  float* t1c = (float*)((char*)rs + 8388608);
  float* t2c = (float*)((char*)rs + 12582912);
  float* t2s = xs;                           // xs dead after conv layer 1
  float* t2o = xc;                           // xc dead after conv layer 1

  k_statsrs<<<661, 256, 0, stream>>>(
      corr, st_ss, rs, (const float*)d_in[9], (const float*)d_in[11],
      (const float*)d_in[15], (const float*)d_in[17], (const float*)d_in[21],
      (const float*)d_in[23], wT, w1s, w2s, w1c, w2c, wmT);
  k_topk<<<256, 256, 0, stream>>>(rs, topidx);
  k_mlp3<<<1024, 512, 0, stream>>>(corr, st_ss, topidx, wmT, b1s, b2s, b1c,
                                   b2c, xs, xc);
  // conv layer 1 (all heads): xs->t1s, xc->t1o, xc->t1c
  k_conv3h<true><<<384, 256, 0, stream>>>(
      xs, xc, xc, wT, wT + 2 * 36864, wT + 4 * 36864,
      (const float*)d_in[10], (const float*)d_in[16], (const float*)d_in[22],
      t1s, t1o, t1c);
  // conv layer 2 (all heads): t1*->t2*
  k_conv3h<true><<<384, 256, 0, stream>>>(
      t1s, t1o, t1c, wT + 1 * 36864, wT + 3 * 36864, wT + 5 * 36864,
      (const float*)d_in[12], (const float*)d_in[18], (const float*)d_in[24],
      t2s, t2o, t2c);
  // conv layer 3 (all heads): t2* -> scales/offsets/scores
  k_convSh<<<768, 256, 0, stream>>>(
      t2s, t2o, t2c, (const float*)d_in[13], (const float*)d_in[19],
      (const float*)d_in[25], (const float*)d_in[14], (const float*)d_in[20],
      (const float*)d_in[26], scales, offsets, scores);

  k_final<<<4, 256, 0, stream>>>(scores, scales, offsets, pos, sclo);
}

// Round 9
// 587.412 us; speedup vs baseline: 1.0591x; 1.0591x over previous
//
#include <hip/hip_runtime.h>

#define HW 4096

// ------- kernel A: fused instance-norm stats + ref_score (1 HBM pass over corr)
// blocks 0..511: one (q,r,ns) group each (18 ch x 4096 px = 295 KB).
//   pass 1: per-channel sum/sumsq (reg acc + xor-shuffle + LDS combine)
//   pass 2: re-read (L2/L3-hot) -> rs = mean_c(x*scl+shf)/18
// ss output: float2 (scl, shf) interleaved.
// blocks 512..660: weight transposes (conv + MLP), independent work.
__global__ __launch_bounds__(256) void k_statsrs(
    const float* __restrict__ corr, float2* __restrict__ ss,
    float* __restrict__ rs,
    const float* __restrict__ p0, const float* __restrict__ p1,
    const float* __restrict__ p2, const float* __restrict__ p3,
    const float* __restrict__ p4, const float* __restrict__ p5,
    float* __restrict__ wT, const float* __restrict__ w1s,
    const float* __restrict__ w2s, const float* __restrict__ w1c,
    const float* __restrict__ w2c, float* __restrict__ wm) {
  int t = threadIdx.x;
  if (blockIdx.x >= 512) {
    int b = blockIdx.x - 512;  // 96 conv chunks + 53 mlp chunks
    if (b < 96) {
      int arr = b >> 4;
      int chunk = b & 15;
      const float* src = (arr == 0) ? p0
                         : (arr == 1) ? p1
                         : (arr == 2) ? p2
                         : (arr == 3) ? p3
                         : (arr == 4) ? p4 : p5;
      float* dst = wT + arr * 36864;
#pragma unroll
      for (int i = 0; i < 9; i++) {
        int e = chunk * 2304 + i * 256 + t;  // 0..36863
        int oc = e / 576;
        int rem = e - oc * 576;  // ic*9+j
        dst[rem * 64 + oc] = src[e];
      }
    } else {
      int i = (b - 96) * 256 + t;
      if (i < 4608) {
        int c = i >> 6, o = i & 63;
        wm[i] = w1s[o * 72 + c];
      } else if (i < 8704) {
        int j = i - 4608;
        int c = j >> 6, o = j & 63;
        wm[i] = w2s[o * 64 + c];
      } else if (i < 9472) {
        int j = i - 8704;
        int c = j >> 6, o = j & 63;
        wm[i] = w1c[o * 12 + c];
      } else if (i < 13568) {
        int j = i - 9472;
        int c = j >> 6, o = j & 63;
        wm[i] = w2c[o * 64 + c];
      }
    }
    return;
  }
  int g = blockIdx.x;  // (q*32+r)*4+ns
  const float4* p = (const float4*)(corr + (size_t)g * 18 * HW);

  // ---- pass 1: per-channel stats, 18 reg accumulators (static idx only)
  float s[18], s2[18];
#pragma unroll
  for (int c = 0; c < 18; c++) { s[c] = 0.f; s2[c] = 0.f; }
#pragma unroll
  for (int c = 0; c < 18; c++) {
#pragma unroll
    for (int i = 0; i < 4; i++) {
      float4 v = p[(c << 10) + (i << 8) + t];
      s[c] += v.x + v.y + v.z + v.w;
      s2[c] += v.x * v.x + v.y * v.y + v.z * v.z + v.w * v.w;
    }
  }
#pragma unroll
  for (int c = 0; c < 18; c++) {
#pragma unroll
    for (int o = 1; o < 64; o <<= 1) {
      s[c] += __shfl_xor(s[c], o, 64);
      s2[c] += __shfl_xor(s2[c], o, 64);
    }
  }
  __shared__ float lds_s[4][18], lds_s2[4][18];
  __shared__ float lds_scl[18], lds_shf[18];
  int wid = t >> 6;
  int ln = t & 63;
  if (ln < 18) {
    float vs = 0.f, vs2 = 0.f;
#pragma unroll
    for (int c = 0; c < 18; c++) {
      vs = (ln == c) ? s[c] : vs;
      vs2 = (ln == c) ? s2[c] : vs2;
    }
    lds_s[wid][ln] = vs;
    lds_s2[wid][ln] = vs2;
  }
  __syncthreads();
  if (t < 18) {
    float S = lds_s[0][t] + lds_s[1][t] + lds_s[2][t] + lds_s[3][t];
    float S2 = lds_s2[0][t] + lds_s2[1][t] + lds_s2[2][t] + lds_s2[3][t];
    float m = S * (1.f / HW);
    float var = S2 * (1.f / HW) - m * m;
    float r = rsqrtf(var + 1e-5f);
    ss[g * 18 + t] = make_float2(r, -m * r);
    lds_scl[t] = r;
    lds_shf[t] = -m * r;
  }
  __syncthreads();

  // ---- pass 2: re-read (cache-hot), rs = (sum_c x*scl + sum_c shf)/18
  float shsum = 0.f;
#pragma unroll
  for (int c = 0; c < 18; c++) shsum += lds_shf[c];
  const float inv = 1.f / 18.f;
#pragma unroll
  for (int i = 0; i < 4; i++) {
    float4 acc = make_float4(0.f, 0.f, 0.f, 0.f);
#pragma unroll
    for (int c = 0; c < 18; c++) {
      float4 v = p[(c << 10) + (i << 8) + t];
      float sc = lds_scl[c];
      acc.x = fmaf(v.x, sc, acc.x);
      acc.y = fmaf(v.y, sc, acc.y);
      acc.z = fmaf(v.z, sc, acc.z);
      acc.w = fmaf(v.w, sc, acc.w);
    }
    float4 o;
    o.x = (acc.x + shsum) * inv;
    o.y = (acc.y + shsum) * inv;
    o.z = (acc.z + shsum) * inv;
    o.w = (acc.w + shsum) * inv;
    ((float4*)(rs + (size_t)g * HW))[(i << 8) + t] = o;
  }
}

// ---------------- kernel C: top-4 of 32, LDS-staged ----------------
__global__ __launch_bounds__(256) void k_topk(const float* __restrict__ rs,
                                              int* __restrict__ topidx) {
  __shared__ float st[32 * 256];  // 32 KB
  int b = blockIdx.x;             // 256 = q*4ns*16pxc
  int pxc = b & 15;
  int ns = (b >> 4) & 3;
  int q = b >> 6;
  int t = threadIdx.x;
  int pxb = pxc * 256;
#pragma unroll 8
  for (int r = 0; r < 32; r++)
    st[r * 256 + t] = rs[((q * 32 + r) * 4 + ns) * HW + pxb + t];
  __syncthreads();
  float v[32];
#pragma unroll
  for (int r = 0; r < 32; r++) v[r] = st[r * 256 + t];
  unsigned mask = 0;
  int sel[4];
#pragma unroll
  for (int k = 0; k < 4; k++) {
    float best = -3.4e38f;
    int bi = 0;
#pragma unroll
    for (int r = 0; r < 32; r++) {
      bool take = (!(mask & (1u << r))) && (v[r] > best);
      best = take ? v[r] : best;
      bi = take ? r : bi;
    }
    sel[k] = bi;
    mask |= (1u << bi);
  }
  ((int4*)topidx)[(q * 4 + ns) * HW + pxb + t] =
      make_int4(sel[0], sel[1], sel[2], sel[3]);
}

// -------- kernel D1: high-occupancy streaming gather+norm -> vbuf ----------
// (round-5-proven structure: 4608 blocks = 18/CU, coalesced 1 KB lines/load)
__global__ __launch_bounds__(256) void k_gather(const float* __restrict__ corr,
                                                const float2* __restrict__ ss,
                                                const int* __restrict__ topidx,
                                                float* __restrict__ vbuf) {
  __shared__ float ls[32], lsh[32];
  int b = blockIdx.x;  // 4608 = q x pxc x ns x c
  int c = b % 18;
  int rest = b / 18;
  int ns = rest & 3;
  int pxc = (rest >> 2) & 15;
  int q = rest >> 6;
  int t = threadIdx.x;
  int px = pxc * 256 + t;

  if (t < 32) {
    float2 v2 = ss[q * 2304 + t * 72 + ns * 18 + c];
    ls[t] = v2.x;
    lsh[t] = v2.y;
  }
  int4 ti = ((const int4*)topidx)[(q * 4 + ns) * HW + px];
  int rk0 = ti.x, rk1 = ti.y, rk2 = ti.z, rk3 = ti.w;
  __syncthreads();

  const float* base = corr + (size_t)(((q * 32) * 4 + ns) * 18 + c) * HW + px;
  float v0 = 0.f, v1 = 0.f, v2 = 0.f, v3 = 0.f;
#pragma unroll
  for (int r = 0; r < 32; r++) {
    float x = base[(size_t)r * 72 * HW];
    v0 = (rk0 == r) ? x : v0;
    v1 = (rk1 == r) ? x : v1;
    v2 = (rk2 == r) ? x : v2;
    v3 = (rk3 == r) ? x : v3;
  }
  v0 = v0 * ls[rk0] + lsh[rk0];
  v1 = v1 * ls[rk1] + lsh[rk1];
  v2 = v2 * ls[rk2] + lsh[rk2];
  v3 = v3 * ls[rk3] + lsh[rk3];
  size_t ob = (size_t)((q * 4 + ns) * 72 + c) * HW + px;
  vbuf[ob] = v0;
  vbuf[ob + 18 * HW] = v1;
  vbuf[ob + 36 * HW] = v2;
  vbuf[ob + 54 * HW] = v3;
}

// ---- kernel D2: both MLPs, 512 thr, 8 osegs x 8 ch, coalesced vbuf staging.
// grid 1024 = q(4) x pxg(256 groups of 16 px).
// thread = oseg(8) x ns(4) x pxi(16).  MLP body identical to verified r6-r8.
// LDS: lx 18KB + lh 16KB + lxsc 3KB = 37.4KB.
__global__ __launch_bounds__(512, 4) void k_mlp4(
    const float* __restrict__ vbuf, const float* __restrict__ wm,
    const float* __restrict__ b1s, const float* __restrict__ b2s,
    const float* __restrict__ b1c, const float* __restrict__ b2c,
    float* __restrict__ xs, float* __restrict__ xc) {
  __shared__ float lx[72 * 64];    // staged x; later reused for a
  __shared__ float lh[64 * 64];    // hidden exchange
  __shared__ float lxsc[12 * 64];  // level means (score-path input)
  int blk = blockIdx.x;
  int q = blk >> 8, pxg = blk & 255;
  int t = threadIdx.x;
  int wi = t & 63;      // ns*16 + pxi
  int oseg = t >> 6;    // wave-uniform 0..7
  int px0 = pxg * 16;

  // stage x from vbuf (coalesced 64B lines per (ns,c))
  const float* vq = vbuf + (size_t)(q * 4) * 72 * HW + px0;
#pragma unroll
  for (int j = 0; j < 9; j++) {
    int e = j * 512 + t;  // 0..4607
    int c = e >> 6;
    int w2 = e & 63;
    int nns = w2 >> 4, ppx = w2 & 15;
    lx[c * 64 + w2] = vq[(size_t)(nns * 72 + c) * HW + ppx];
  }
  __syncthreads();  // #1: lx complete

  // level means: lxsc[l][col], 768 entries over 512 threads
#pragma unroll
  for (int m = 0; m < 2; m++) {
    int idx = m * 512 + t;
    if (idx < 768) {
      int l = idx >> 6, w2 = idx & 63;
      float sm = 0.f;
#pragma unroll
      for (int j = 0; j < 6; j++) sm += lx[(l * 6 + j) * 64 + w2];
      lxsc[l * 64 + w2] = sm * (1.f / 6.f);
    }
  }

  // ---- scale path layer 1: 72 -> 8 (this thread's segment)
  float h[8];
  const float* bp1 = b1s + oseg * 8;
#pragma unroll
  for (int o = 0; o < 8; o++) h[o] = bp1[o];
#pragma unroll
  for (int c = 0; c < 72; c++) {
    float x = lx[c * 64 + wi];
    const float* wr = wm + c * 64 + oseg * 8;  // wave-uniform -> s_load
#pragma unroll
    for (int o = 0; o < 8; o++) h[o] = fmaf(wr[o], x, h[o]);
  }
#pragma unroll
  for (int o = 0; o < 8; o++) lh[(oseg * 8 + o) * 64 + wi] = fmaxf(h[o], 0.f);
  __syncthreads();  // #2: lh + lxsc complete, all lx reads (l1) done

  // ---- scale path layer 2: 64 -> 8
  float a[8];
  const float* bp2 = b2s + oseg * 8;
#pragma unroll
  for (int o = 0; o < 8; o++) a[o] = bp2[o];
#pragma unroll
  for (int c = 0; c < 64; c++) {
    float x = lh[c * 64 + wi];
    const float* wr = wm + 4608 + c * 64 + oseg * 8;
#pragma unroll
    for (int o = 0; o < 8; o++) a[o] = fmaf(wr[o], x, a[o]);
  }
#pragma unroll
  for (int o = 0; o < 8; o++) lx[(oseg * 8 + o) * 64 + wi] = a[o];
  __syncthreads();  // #3: a staged in lx, all lh reads (l2) done

  // ns-max + store xs (2 per thread); score-path l1 in same phase
#pragma unroll
  for (int m = 0; m < 2; m++) {
    int idx = m * 512 + t;
    int oc = idx >> 4, ppx = idx & 15;
    float v2 = lx[oc * 64 + ppx];
    v2 = fmaxf(v2, lx[oc * 64 + 16 + ppx]);
    v2 = fmaxf(v2, lx[oc * 64 + 32 + ppx]);
    v2 = fmaxf(v2, lx[oc * 64 + 48 + ppx]);
    xs[(size_t)(q * 64 + oc) * HW + px0 + ppx] = v2;
  }
  const float* bc1 = b1c + oseg * 8;
#pragma unroll
  for (int o = 0; o < 8; o++) h[o] = bc1[o];
#pragma unroll
  for (int c = 0; c < 12; c++) {
    float x = lxsc[c * 64 + wi];
    const float* wr = wm + 8704 + c * 64 + oseg * 8;
#pragma unroll
    for (int o = 0; o < 8; o++) h[o] = fmaf(wr[o], x, h[o]);
  }
#pragma unroll
  for (int o = 0; o < 8; o++) lh[(oseg * 8 + o) * 64 + wi] = fmaxf(h[o], 0.f);
  __syncthreads();  // #4: score-h in lh, all xs-max lx reads done

  // ---- score path layer 2: 64 -> 8
  const float* bc2 = b2c + oseg * 8;
#pragma unroll
  for (int o = 0; o < 8; o++) a[o] = bc2[o];
#pragma unroll
  for (int c = 0; c < 64; c++) {
    float x = lh[c * 64 + wi];
    const float* wr = wm + 9472 + c * 64 + oseg * 8;
#pragma unroll
    for (int o = 0; o < 8; o++) a[o] = fmaf(wr[o], x, a[o]);
  }
#pragma unroll
  for (int o = 0; o < 8; o++) lx[(oseg * 8 + o) * 64 + wi] = a[o];
  __syncthreads();  // #5

  // ns-max + store xc
#pragma unroll
  for (int m = 0; m < 2; m++) {
    int idx = m * 512 + t;
    int oc = idx >> 4, ppx = idx & 15;
    float v2 = lx[oc * 64 + ppx];
    v2 = fmaxf(v2, lx[oc * 64 + 16 + ppx]);
    v2 = fmaxf(v2, lx[oc * 64 + 32 + ppx]);
    v2 = fmaxf(v2, lx[oc * 64 + 48 + ppx]);
    xc[(size_t)(q * 64 + oc) * HW + px0 + ppx] = v2;
  }
}

// ---- merged big 3x3 conv v3: 2 rows x 16 oc per thread (og=4).
// grid 384 = hi(12: og*3+head)*32 + q*8 + rt.  Tile: 8 out rows x 64 cols.
// LDS 16ic x 10 rows x 72 stride (data at col 4..67, pads col 3 & 68) = 46 KB.
template <bool RELU>
__global__ __launch_bounds__(256) void k_conv3h(
    const float* __restrict__ in0, const float* __restrict__ in1,
    const float* __restrict__ in2, const float* __restrict__ w0,
    const float* __restrict__ w1, const float* __restrict__ w2,
    const float* __restrict__ bb0, const float* __restrict__ bb1,
    const float* __restrict__ bb2, float* __restrict__ o0,
    float* __restrict__ o1, float* __restrict__ o2) {
  __shared__ float tile[16 * 10 * 72];  // 46.1 KB -> 3 blocks/CU
  int b = blockIdx.x;
  int hi = b >> 5;  // og*3 + head, og in 0..3
  int og = hi / 3;
  int head = hi - og * 3;
  int q = (b >> 3) & 3;
  int rt = b & 7;
  const float* in = head == 0 ? in0 : head == 1 ? in1 : in2;
  const float* wT = head == 0 ? w0 : head == 1 ? w1 : w2;
  const float* bb = head == 0 ? bb0 : head == 1 ? bb1 : bb2;
  float* outp = head == 0 ? o0 : head == 1 ? o1 : o2;

  int t = threadIdx.x;
  int w = t & 63;
  int wr = t >> 6;       // 0..3 (wave-uniform): thread rows 2wr, 2wr+1
  int lane4 = t & 15;    // staging: float4 col
  int rgrp = t >> 4;     // staging: 16 rows/pass
  float acc[2][16];
#pragma unroll
  for (int pr = 0; pr < 2; pr++)
#pragma unroll
    for (int o = 0; o < 16; o++) acc[pr][o] = 0.f;
  const float* inq = in + (size_t)q * 64 * HW;

  for (int icc = 0; icc < 4; icc++) {
    __syncthreads();
    // edge pads (rows 0..159): col 3 (img -1) and col 68 (img 64)
    if (t < 160) { tile[t * 72 + 3] = 0.f; tile[t * 72 + 68] = 0.f; }
    // stage 16 ic x 10 rows x 64 cols as float4
#pragma unroll
    for (int p = 0; p < 10; p++) {
      int idx = p * 16 + rgrp;  // 0..159
      int ch = idx / 10;
      int r = idx - ch * 10;
      int grow = rt * 8 + r - 1;
      float4 val = make_float4(0.f, 0.f, 0.f, 0.f);
      if (grow >= 0 && grow < 64)
        val = *(const float4*)(inq + (size_t)(icc * 16 + ch) * HW + grow * 64 +
                               lane4 * 4);
      *(float4*)(tile + idx * 72 + 4 + lane4 * 4) = val;
    }
    __syncthreads();
#pragma unroll 2
    for (int ic = 0; ic < 16; ic++) {
      // x window: 4 tile rows x 3 cols
      float xv[4][3];
      const float* tb = tile + (ic * 10 + wr * 2) * 72 + w + 3;
#pragma unroll
      for (int rr = 0; rr < 4; rr++)
#pragma unroll
        for (int dc = 0; dc < 3; dc++) xv[rr][dc] = tb[rr * 72 + dc];
      const float* wb = wT + (size_t)(icc * 16 + ic) * 9 * 64 + og * 16;
#pragma unroll
      for (int dr = 0; dr < 3; dr++)
#pragma unroll
        for (int dc = 0; dc < 3; dc++) {
          const float* wv = wb + (dr * 3 + dc) * 64;
#pragma unroll
          for (int o = 0; o < 16; o++) {
            float wj = wv[o];
            acc[0][o] = fmaf(wj, xv[0 + dr][dc], acc[0][o]);
            acc[1][o] = fmaf(wj, xv[1 + dr][dc], acc[1][o]);
          }
        }
    }
  }
#pragma unroll
  for (int pr = 0; pr < 2; pr++) {
    int orow = rt * 8 + wr * 2 + pr;
#pragma unroll
    for (int o = 0; o < 16; o++) {
      float rz = acc[pr][o] + bb[og * 16 + o];
      if (RELU) rz = fmaxf(rz, 0.f);
      outp[((size_t)q * 64 + og * 16 + o) * HW + orow * 64 + w] = rz;
    }
  }
}

// ---- merged small 3x3 conv (heads: OC=1,2,1), 1-row blocks ----
__global__ __launch_bounds__(256) void k_convSh(
    const float* __restrict__ in0, const float* __restrict__ in1,
    const float* __restrict__ in2, const float* __restrict__ wt0,
    const float* __restrict__ wt1, const float* __restrict__ wt2,
    const float* __restrict__ bb0, const float* __restrict__ bb1,
    const float* __restrict__ bb2, float* __restrict__ o0,
    float* __restrict__ o1, float* __restrict__ o2) {
  __shared__ float tile[64 * 3 * 66];  // 50.7 KB
  __shared__ float red[4 * 2 * 64];
  int b = blockIdx.x;  // 768 = head*256 + q*64 + row
  int head = b >> 8;
  int q = (b >> 6) & 3;
  int row = b & 63;
  const float* in = head == 0 ? in0 : head == 1 ? in1 : in2;
  const float* wt = head == 0 ? wt0 : head == 1 ? wt1 : wt2;
  const float* bb = head == 0 ? bb0 : head == 1 ? bb1 : bb2;
  float* outp = head == 0 ? o0 : head == 1 ? o1 : o2;
  int noc = (head == 1) ? 2 : 1;

  int t = threadIdx.x;
  int w = t & 63;
  int sub = t >> 6;
  if (t < 192) { tile[t * 66] = 0.f; tile[t * 66 + 65] = 0.f; }
  __syncthreads();
  const float* inq = in + (size_t)q * 64 * HW;
#pragma unroll
  for (int i = 0; i < 48; i++) {
    int idx = i * 4 + sub;
    int ic = idx / 3;
    int r = idx - ic * 3;
    int grow = row + r - 1;
    float val = 0.f;
    if (grow >= 0 && grow < 64) val = inq[(size_t)ic * HW + grow * 64 + w];
    tile[idx * 66 + 1 + w] = val;
  }
  __syncthreads();
  float acc0 = 0.f, acc1 = 0.f;
#pragma unroll 4
  for (int i = 0; i < 16; i++) {
    int ic = sub * 16 + i;
    float x[9];
#pragma unroll
    for (int dr = 0; dr < 3; dr++)
#pragma unroll
      for (int dc = 0; dc < 3; dc++)
        x[dr * 3 + dc] = tile[(ic * 3 + dr) * 66 + w + dc];
    const float* wb = wt + (size_t)ic * 9;
#pragma unroll
    for (int j = 0; j < 9; j++) acc0 += wb[j] * x[j];
    if (noc == 2) {
      const float* wb1 = wt + 576 + (size_t)ic * 9;
#pragma unroll
      for (int j = 0; j < 9; j++) acc1 += wb1[j] * x[j];
    }
  }
  red[(sub * 2 + 0) * 64 + w] = acc0;
  if (noc == 2) red[(sub * 2 + 1) * 64 + w] = acc1;
  __syncthreads();
  if (t < 128) {
    int o = t >> 6;
    if (o < noc) {
      float s = red[(0 * 2 + o) * 64 + w] + red[(1 * 2 + o) * 64 + w] +
                red[(2 * 2 + o) * 64 + w] + red[(3 * 2 + o) * 64 + w] + bb[o];
      outp[((size_t)q * noc + o) * HW + row * 64 + w] = s;
    }
  }
}

// ---------------- final: argmax + pos/scl ----------------
__global__ __launch_bounds__(256) void k_final(const float* __restrict__ scores,
                                               const float* __restrict__ scales,
                                               const float* __restrict__ offsets,
                                               float* __restrict__ pos,
                                               float* __restrict__ sclo) {
  int q = blockIdx.x, t = threadIdx.x;
  float best = -3.4e38f;
  int bi = 1 << 30;
  for (int i = t; i < HW; i += 256) {
    float v = scores[q * HW + i];
    if (v > best) { best = v; bi = i; }
  }
  __shared__ float bv[256];
  __shared__ int bix[256];
  bv[t] = best;
  bix[t] = bi;
  __syncthreads();
  for (int s = 128; s > 0; s >>= 1) {
    if (t < s) {
      if (bv[t + s] > bv[t] || (bv[t + s] == bv[t] && bix[t + s] < bix[t])) {
        bv[t] = bv[t + s];
        bix[t] = bix[t + s];
      }
    }
    __syncthreads();
  }
  if (t == 0) {
    int sid = bix[0];
    int sy = sid >> 6, sx = sid & 63;
    float o0 = offsets[(q * 2 + 0) * HW + sid];
    float o1 = offsets[(q * 2 + 1) * HW + sid];
    pos[q * 2 + 0] = ((float)sx + o0 + 0.5f) * 8.f - 0.5f;
    pos[q * 2 + 1] = ((float)sy + o1 + 0.5f) * 8.f - 0.5f;
    sclo[q] = exp2f(scales[q * HW + sid]);
  }
}

extern "C" void kernel_launch(void* const* d_in, const int* in_sizes, int n_in,
                              void* d_out, int out_size, void* d_ws, size_t ws_size,
                              hipStream_t stream) {
  const float* corr = (const float*)d_in[0];
  const float* w1s = (const float*)d_in[1];
  const float* b1s = (const float*)d_in[2];
  const float* w2s = (const float*)d_in[3];
  const float* b2s = (const float*)d_in[4];
  const float* w1c = (const float*)d_in[5];
  const float* b1c = (const float*)d_in[6];
  const float* w2c = (const float*)d_in[7];
  const float* b2c = (const float*)d_in[8];

  float* out = (float*)d_out;
  float* pos = out;                   // (4,2)
  float* sclo = out + 8;              // (4,)
  float* scores = out + 12;           // (4,1,64,64)
  float* scales = out + 12 + 16384;   // (4,1,64,64)
  float* offsets = out + 12 + 32768;  // (4,2,64,64)

  char* ws = (char*)d_ws;
  float2* st_ss = (float2*)(ws + 0);      // 72 KB (scl,shf interleaved)
  int* topidx = (int*)(ws + 73728);       // 1 MB
  float* rs = (float*)(ws + 1122304);     // 8.39 MB (dead after k_topk)
  float* vbuf = rs;                       // 18.87 MB, overlaps rs (ok)
  float* wT = (float*)(ws + 19996672);    // 884 KB (big-conv transposed w)
  float* wmT = (float*)(ws + 20881408);   // 54 KB (MLP transposed w)
  float* xs = (float*)(ws + 20971520);    // 4.19 MB
  float* xc = (float*)(ws + 25165824);    // 4.19 MB  (total 29.4 MB)
  // t1/t2 reuse dead regions (stream-ordered):
  float* t1s = vbuf;                         // vbuf dead after k_mlp4
  float* t1o = (float*)((char*)vbuf + 4194304);
  float* t1c = (float*)((char*)vbuf + 8388608);
  float* t2c = (float*)((char*)vbuf + 12582912);
  float* t2s = xs;                           // xs dead after conv layer 1
  float* t2o = xc;                           // xc dead after conv layer 1

  k_statsrs<<<661, 256, 0, stream>>>(
      corr, st_ss, rs, (const float*)d_in[9], (const float*)d_in[11],
      (const float*)d_in[15], (const float*)d_in[17], (const float*)d_in[21],
      (const float*)d_in[23], wT, w1s, w2s, w1c, w2c, wmT);
  k_topk<<<256, 256, 0, stream>>>(rs, topidx);
  k_gather<<<4608, 256, 0, stream>>>(corr, st_ss, topidx, vbuf);
  k_mlp4<<<1024, 512, 0, stream>>>(vbuf, wmT, b1s, b2s, b1c, b2c, xs, xc);
  // conv layer 1 (all heads): xs->t1s, xc->t1o, xc->t1c
  k_conv3h<true><<<384, 256, 0, stream>>>(
      xs, xc, xc, wT, wT + 2 * 36864, wT + 4 * 36864,
      (const float*)d_in[10], (const float*)d_in[16], (const float*)d_in[22],
      t1s, t1o, t1c);
  // conv layer 2 (all heads): t1*->t2*
  k_conv3h<true><<<384, 256, 0, stream>>>(
      t1s, t1o, t1c, wT + 1 * 36864, wT + 3 * 36864, wT + 5 * 36864,
      (const float*)d_in[12], (const float*)d_in[18], (const float*)d_in[24],
      t2s, t2o, t2c);
  // conv layer 3 (all heads): t2* -> scales/offsets/scores
  k_convSh<<<768, 256, 0, stream>>>(
      t2s, t2o, t2c, (const float*)d_in[13], (const float*)d_in[19],
      (const float*)d_in[25], (const float*)d_in[14], (const float*)d_in[20],
      (const float*)d_in[26], scales, offsets, scores);

  k_final<<<4, 256, 0, stream>>>(scores, scales, offsets, pos, sclo);
}